// Round 1
// baseline (1309.469 us; speedup 1.0000x reference)
//
#include <hip/hip_runtime.h>

// Problem constants (match reference)
constexpr int NN = 50000;      // nodes
constexpr int NE = 800000;     // edges
constexpr int F_IN = 128;
constexpr int D0 = 256;
constexpr int D1 = 64;
constexpr int NG = 256;        // graphs
constexpr float EPS_BN = 1e-5f;

// ---------------- edge sort (counting sort by dst) ----------------
__global__ __launch_bounds__(256) void k_hist(const int* __restrict__ ei, int* __restrict__ cnt) {
    int e = blockIdx.x * 256 + threadIdx.x;
    if (e < NE) atomicAdd(&cnt[ei[NE + e]], 1);
}

// single-block 1024-thread chunked Hillis-Steele exclusive scan over NN counts
__global__ __launch_bounds__(1024) void k_scan(const int* __restrict__ cnt,
                                               int* __restrict__ offs,
                                               int* __restrict__ cursor) {
    __shared__ int lds[1024];
    __shared__ int carry_s;
    int t = threadIdx.x;
    if (t == 0) carry_s = 0;
    __syncthreads();
    for (int base = 0; base < NN; base += 1024) {
        int idx = base + t;
        int v = (idx < NN) ? cnt[idx] : 0;
        lds[t] = v;
        __syncthreads();
        for (int off = 1; off < 1024; off <<= 1) {
            int addv = (t >= off) ? lds[t - off] : 0;
            __syncthreads();
            lds[t] += addv;
            __syncthreads();
        }
        int incl = lds[t];
        int excl = incl - v;
        int carry = carry_s;
        if (idx < NN) {
            offs[idx] = carry + excl;
            cursor[idx] = carry + excl;
        }
        __syncthreads();
        if (t == 1023) carry_s = carry + incl;
        __syncthreads();
    }
    if (t == 0) offs[NN] = NE;
}

__global__ __launch_bounds__(256) void k_scatter(const int* __restrict__ ei,
                                                 const float* __restrict__ ea,
                                                 int* __restrict__ cursor,
                                                 int* __restrict__ ssrc,
                                                 float* __restrict__ sea) {
    int e = blockIdx.x * 256 + threadIdx.x;
    if (e < NE) {
        int d = ei[NE + e];
        int pos = atomicAdd(&cursor[d], 1);
        ssrc[pos] = ei[e];
        sea[pos] = ea[e];
    }
}

// ---------------- fused 4-matrix GEMM:  O_m = X @ W_m + b_m ----------------
// 64x64 output tile, 256 threads, each 4x4 micro-tile, K-step 64.
template<int K, int DOUT>
__global__ __launch_bounds__(256) void k_gemm4(
    const float* __restrict__ X,
    const float* __restrict__ W0, const float* __restrict__ B0,
    const float* __restrict__ W1, const float* __restrict__ B1,
    const float* __restrict__ W2, const float* __restrict__ B2,
    const float* __restrict__ W3, const float* __restrict__ B3,
    float* __restrict__ O0, float* __restrict__ O1,
    float* __restrict__ O2, float* __restrict__ O3)
{
    __shared__ float Xs[64][68];   // 68-float stride: rows 16B-aligned, conflict-light
    __shared__ float Ws[64][68];
    int row0 = blockIdx.x * 64;
    int col0g = blockIdx.y * 64;
    int mat = col0g / DOUT;
    int col0 = col0g - mat * DOUT;
    const float* W = (mat == 0) ? W0 : (mat == 1) ? W1 : (mat == 2) ? W2 : W3;
    const float* B = (mat == 0) ? B0 : (mat == 1) ? B1 : (mat == 2) ? B2 : B3;
    float* O = (mat == 0) ? O0 : (mat == 1) ? O1 : (mat == 2) ? O2 : O3;

    int t = threadIdx.x;
    int tx = t & 15, ty = t >> 4;
    float acc[4][4] = {};

    for (int k0 = 0; k0 < K; k0 += 64) {
        #pragma unroll
        for (int i = 0; i < 4; ++i) {
            int lin = t + i * 256;           // float4 slot
            int r = lin >> 4, c4 = lin & 15;
            int gr = row0 + r;
            float4 val = make_float4(0.f, 0.f, 0.f, 0.f);
            if (gr < NN) val = *reinterpret_cast<const float4*>(&X[(size_t)gr * K + k0 + c4 * 4]);
            *reinterpret_cast<float4*>(&Xs[r][c4 * 4]) = val;
        }
        #pragma unroll
        for (int i = 0; i < 4; ++i) {
            int lin = t + i * 256;
            int r = lin >> 4, c4 = lin & 15;
            float4 val = *reinterpret_cast<const float4*>(&W[(size_t)(k0 + r) * DOUT + col0 + c4 * 4]);
            *reinterpret_cast<float4*>(&Ws[r][c4 * 4]) = val;
        }
        __syncthreads();
        #pragma unroll
        for (int kk = 0; kk < 64; ++kk) {
            float xv[4];
            #pragma unroll
            for (int i = 0; i < 4; ++i) xv[i] = Xs[ty * 4 + i][kk];
            float4 wv = *reinterpret_cast<const float4*>(&Ws[kk][tx * 4]);
            #pragma unroll
            for (int i = 0; i < 4; ++i) {
                acc[i][0] += xv[i] * wv.x;
                acc[i][1] += xv[i] * wv.y;
                acc[i][2] += xv[i] * wv.z;
                acc[i][3] += xv[i] * wv.w;
            }
        }
        __syncthreads();
    }
    #pragma unroll
    for (int i = 0; i < 4; ++i) {
        int gr = row0 + ty * 4 + i;
        if (gr >= NN) continue;
        #pragma unroll
        for (int j = 0; j < 4; ++j) {
            int gc = col0 + tx * 4 + j;
            O[(size_t)gr * DOUT + gc] = acc[i][j] + B[gc];
        }
    }
}

// ---------------- per-node attention aggregate (1 wave / node, 2 passes) ----------------
template<int D>
__global__ __launch_bounds__(256) void k_attn(
    const float* __restrict__ q, const float* __restrict__ k, const float* __restrict__ v,
    const float* __restrict__ We,           // [D]
    const int* __restrict__ ssrc, const float* __restrict__ sea,
    const int* __restrict__ offs,
    float* __restrict__ logits,             // [NE] scratch (sorted-edge order)
    float* __restrict__ hout)               // [NN,D], pre-loaded with skip; += attn out
{
    int wave = threadIdx.x >> 6;
    int lane = threadIdx.x & 63;
    int node = blockIdx.x * 4 + wave;
    if (node >= NN) return;
    int start = offs[node], stop = offs[node + 1];
    constexpr float inv_sqrt_d = (D == 256) ? 0.0625f : 0.125f;

    if constexpr (D == 256) {
        float4 qv = *reinterpret_cast<const float4*>(&q[(size_t)node * 256 + lane * 4]);
        float4 wel = *reinterpret_cast<const float4*>(&We[lane * 4]);
        float m = -1e30f;
        for (int i = start; i < stop; ++i) {
            int s = ssrc[i];
            float eav = sea[i];
            float4 kv = *reinterpret_cast<const float4*>(&k[(size_t)s * 256 + lane * 4]);
            float dot = qv.x * (kv.x + eav * wel.x) + qv.y * (kv.y + eav * wel.y)
                      + qv.z * (kv.z + eav * wel.z) + qv.w * (kv.w + eav * wel.w);
            #pragma unroll
            for (int o = 32; o; o >>= 1) dot += __shfl_xor(dot, o);
            dot *= inv_sqrt_d;
            if (lane == 0) logits[i] = dot;
            m = fmaxf(m, dot);
        }
        float ssum = 0.f;
        float4 acc = make_float4(0.f, 0.f, 0.f, 0.f);
        for (int i = start; i < stop; ++i) {
            int s = ssrc[i];
            float eav = sea[i];
            float p = expf(logits[i] - m);
            ssum += p;
            float4 vv = *reinterpret_cast<const float4*>(&v[(size_t)s * 256 + lane * 4]);
            acc.x += p * (vv.x + eav * wel.x);
            acc.y += p * (vv.y + eav * wel.y);
            acc.z += p * (vv.z + eav * wel.z);
            acc.w += p * (vv.w + eav * wel.w);
        }
        float inv = 1.0f / (ssum + 1e-16f);
        float* hp = &hout[(size_t)node * 256 + lane * 4];
        float4 cur = *reinterpret_cast<float4*>(hp);
        cur.x += acc.x * inv; cur.y += acc.y * inv;
        cur.z += acc.z * inv; cur.w += acc.w * inv;
        *reinterpret_cast<float4*>(hp) = cur;
    } else {
        float qv = q[(size_t)node * 64 + lane];
        float wel = We[lane];
        float m = -1e30f;
        for (int i = start; i < stop; ++i) {
            int s = ssrc[i];
            float eav = sea[i];
            float kv = k[(size_t)s * 64 + lane];
            float dot = qv * (kv + eav * wel);
            #pragma unroll
            for (int o = 32; o; o >>= 1) dot += __shfl_xor(dot, o);
            dot *= inv_sqrt_d;
            if (lane == 0) logits[i] = dot;
            m = fmaxf(m, dot);
        }
        float ssum = 0.f, acc = 0.f;
        for (int i = start; i < stop; ++i) {
            int s = ssrc[i];
            float eav = sea[i];
            float p = expf(logits[i] - m);
            ssum += p;
            float vv = v[(size_t)s * 64 + lane];
            acc += p * (vv + eav * wel);
        }
        float inv = 1.0f / (ssum + 1e-16f);
        hout[(size_t)node * 64 + lane] += acc * inv;
    }
}

// ---------------- BatchNorm ----------------
template<int D>
__global__ __launch_bounds__(256) void k_bnstats(const float* __restrict__ h,
                                                 float* __restrict__ sums,   // [2D]: sum, sumsq
                                                 int rows_per_block) {
    constexpr int NSUB = 256 / D;
    int col = threadIdx.x % D;
    int sub = threadIdx.x / D;
    int r0 = blockIdx.x * rows_per_block;
    int r1 = min(r0 + rows_per_block, NN);
    float s = 0.f, ss = 0.f;
    for (int r = r0 + sub; r < r1; r += NSUB) {
        float x = h[(size_t)r * D + col];
        s += x; ss += x * x;
    }
    atomicAdd(&sums[col], s);
    atomicAdd(&sums[D + col], ss);
}

template<int D>
__global__ void k_bnfin(const float* __restrict__ sums,
                        const float* __restrict__ gamma, const float* __restrict__ beta,
                        float* __restrict__ ab) {       // [2D]: a, b
    int c = threadIdx.x;
    if (c >= D) return;
    float mean = sums[c] / (float)NN;
    float var = sums[D + c] / (float)NN - mean * mean;
    float a = gamma[c] * rsqrtf(var + EPS_BN);
    ab[c] = a;
    ab[D + c] = beta[c] - mean * a;
}

// h0: normalize in place (layer-1 input) and write xs[:, 0:256]
__global__ __launch_bounds__(256) void k_bnapply0(float* __restrict__ h,
                                                  const float* __restrict__ ab,
                                                  float* __restrict__ xs) {
    int idx = blockIdx.x * 256 + threadIdx.x;     // over NN*64 float4s
    int n = idx >> 6, c4 = idx & 63;
    float4 x4 = *reinterpret_cast<float4*>(&h[(size_t)idx * 4]);
    float4 a4 = *reinterpret_cast<const float4*>(&ab[c4 * 4]);
    float4 b4 = *reinterpret_cast<const float4*>(&ab[256 + c4 * 4]);
    float4 r;
    r.x = a4.x * x4.x + b4.x; r.y = a4.y * x4.y + b4.y;
    r.z = a4.z * x4.z + b4.z; r.w = a4.w * x4.w + b4.w;
    *reinterpret_cast<float4*>(&h[(size_t)idx * 4]) = r;
    *reinterpret_cast<float4*>(&xs[(size_t)n * 320 + c4 * 4]) = r;
}

// h1: write only xs[:, 256:320]
__global__ __launch_bounds__(256) void k_bnapply1(const float* __restrict__ h,
                                                  const float* __restrict__ ab,
                                                  float* __restrict__ xs) {
    int idx = blockIdx.x * 256 + threadIdx.x;     // over NN*16 float4s
    int n = idx >> 4, c4 = idx & 15;
    float4 x4 = *reinterpret_cast<const float4*>(&h[(size_t)idx * 4]);
    float4 a4 = *reinterpret_cast<const float4*>(&ab[c4 * 4]);
    float4 b4 = *reinterpret_cast<const float4*>(&ab[64 + c4 * 4]);
    float4 r;
    r.x = a4.x * x4.x + b4.x; r.y = a4.y * x4.y + b4.y;
    r.z = a4.z * x4.z + b4.z; r.w = a4.w * x4.w + b4.w;
    *reinterpret_cast<float4*>(&xs[(size_t)n * 320 + 256 + c4 * 4]) = r;
}

// ---------------- global mean pool (1 block / graph, batch sorted) ----------------
__global__ __launch_bounds__(256) void k_pool(const float* __restrict__ xs,
                                              const int* __restrict__ batch,
                                              float* __restrict__ xpool) {
    int g = blockIdx.x;
    __shared__ int se[2];
    if (threadIdx.x < 2) {
        int target = g + threadIdx.x;
        int lo = 0, hi = NN;
        while (lo < hi) {
            int mid = (lo + hi) >> 1;
            if (batch[mid] < target) lo = mid + 1; else hi = mid;
        }
        se[threadIdx.x] = lo;
    }
    __syncthreads();
    int start = se[0], stop = se[1];
    float cnt = fmaxf((float)(stop - start), 1.0f);
    for (int c = threadIdx.x; c < 320; c += 256) {
        float s = 0.f;
        for (int r = start; r < stop; ++r) s += xs[(size_t)r * 320 + c];
        xpool[(size_t)g * 320 + c] = s / cnt;
    }
}

// ---------------- launch ----------------
extern "C" void kernel_launch(void* const* d_in, const int* in_sizes, int n_in,
                              void* d_out, int out_size, void* d_ws, size_t ws_size,
                              hipStream_t stream) {
    const float* x     = (const float*)d_in[0];
    const int*   ei    = (const int*)d_in[1];
    const float* ea    = (const float*)d_in[2];
    const int*   batch = (const int*)d_in[3];
    const float *Wq0 = (const float*)d_in[4],  *bq0 = (const float*)d_in[5];
    const float *Wk0 = (const float*)d_in[6],  *bk0 = (const float*)d_in[7];
    const float *Wv0 = (const float*)d_in[8],  *bv0 = (const float*)d_in[9];
    const float *We0 = (const float*)d_in[10];
    const float *Ws0 = (const float*)d_in[11], *bs0 = (const float*)d_in[12];
    const float *gamma0 = (const float*)d_in[13], *beta0 = (const float*)d_in[14];
    const float *Wq1 = (const float*)d_in[15], *bq1 = (const float*)d_in[16];
    const float *Wk1 = (const float*)d_in[17], *bk1 = (const float*)d_in[18];
    const float *Wv1 = (const float*)d_in[19], *bv1 = (const float*)d_in[20];
    const float *We1 = (const float*)d_in[21];
    const float *Ws1 = (const float*)d_in[22], *bs1 = (const float*)d_in[23];
    const float *gamma1 = (const float*)d_in[24], *beta1 = (const float*)d_in[25];

    char* ws = (char*)d_ws;
    size_t off = 0;
    auto alloc = [&](size_t bytes) -> char* {
        char* p = ws + off;
        off += (bytes + 255) & ~(size_t)255;
        return p;
    };
    float* q0 = (float*)alloc((size_t)NN * D0 * 4);   // reused later for q1,k1,v1,h1
    float* k0 = (float*)alloc((size_t)NN * D0 * 4);
    float* v0 = (float*)alloc((size_t)NN * D0 * 4);
    float* h0 = (float*)alloc((size_t)NN * D0 * 4);
    float* logits = (float*)alloc((size_t)NE * 4);
    float* sea    = (float*)alloc((size_t)NE * 4);
    int*   ssrc   = (int*)alloc((size_t)NE * 4);
    int*   cnt    = (int*)alloc((size_t)(NN + 1) * 4);
    int*   offs   = (int*)alloc((size_t)(NN + 1) * 4);
    int*   cursor = (int*)alloc((size_t)(NN + 1) * 4);
    float* sums0  = (float*)alloc(2 * D0 * 4);
    float* ab0    = (float*)alloc(2 * D0 * 4);
    float* sums1  = (float*)alloc(2 * D1 * 4);
    float* ab1    = (float*)alloc(2 * D1 * 4);

    // layer-1 buffers alias q0's block (q0 dead after attn0)
    float* q1 = q0;
    float* k1 = q0 + (size_t)NN * D1;
    float* v1 = q0 + (size_t)2 * NN * D1;
    float* h1 = q0 + (size_t)3 * NN * D1;

    float* xpool = (float*)d_out;
    float* xs = (float*)d_out + (size_t)NG * 320;

    // --- edge sort ---
    hipMemsetAsync(cnt, 0, (NN + 1) * 4, stream);
    k_hist<<<(NE + 255) / 256, 256, 0, stream>>>(ei, cnt);
    k_scan<<<1, 1024, 0, stream>>>(cnt, offs, cursor);
    k_scatter<<<(NE + 255) / 256, 256, 0, stream>>>(ei, ea, cursor, ssrc, sea);

    // --- layer 0 ---
    k_gemm4<F_IN, D0><<<dim3((NN + 63) / 64, 16), 256, 0, stream>>>(
        x, Wq0, bq0, Wk0, bk0, Wv0, bv0, Ws0, bs0, q0, k0, v0, h0);
    k_attn<D0><<<(NN + 3) / 4, 256, 0, stream>>>(q0, k0, v0, We0, ssrc, sea, offs, logits, h0);
    hipMemsetAsync(sums0, 0, 2 * D0 * 4, stream);
    k_bnstats<D0><<<(NN + 255) / 256, 256, 0, stream>>>(h0, sums0, 256);
    k_bnfin<D0><<<1, D0, 0, stream>>>(sums0, gamma0, beta0, ab0);
    k_bnapply0<<<(NN * 64 + 255) / 256, 256, 0, stream>>>(h0, ab0, xs);

    // --- layer 1 ---
    k_gemm4<D0, D1><<<dim3((NN + 63) / 64, 4), 256, 0, stream>>>(
        h0, Wq1, bq1, Wk1, bk1, Wv1, bv1, Ws1, bs1, q1, k1, v1, h1);
    k_attn<D1><<<(NN + 3) / 4, 256, 0, stream>>>(q1, k1, v1, We1, ssrc, sea, offs, logits, h1);
    hipMemsetAsync(sums1, 0, 2 * D1 * 4, stream);
    k_bnstats<D1><<<(NN + 255) / 256, 256, 0, stream>>>(h1, sums1, 256);
    k_bnfin<D1><<<1, D1, 0, stream>>>(sums1, gamma1, beta1, ab1);
    k_bnapply1<<<(NN * 16 + 255) / 256, 256, 0, stream>>>(h1, ab1, xs);

    // --- pool ---
    k_pool<<<NG, 256, 0, stream>>>(xs, batch, xpool);
}

// Round 2
// 962.024 us; speedup vs baseline: 1.3612x; 1.3612x over previous
//
#include <hip/hip_runtime.h>

// Problem constants (match reference)
constexpr int NN = 50000;      // nodes
constexpr int NE = 800000;     // edges
constexpr int F_IN = 128;
constexpr int D0 = 256;
constexpr int D1 = 64;
constexpr int NG = 256;        // graphs
constexpr float EPS_BN = 1e-5f;

typedef __attribute__((ext_vector_type(8))) short bf16x8;
typedef __attribute__((ext_vector_type(4))) float f32x4;

__device__ inline ushort f2bf(float f) {
    uint32_t u = __float_as_uint(f);
    uint32_t r = u + 0x7fff + ((u >> 16) & 1);   // RNE
    return (ushort)(r >> 16);
}
__device__ inline float bf2f(ushort b) {
    return __uint_as_float((uint32_t)b << 16);
}

// ---------------- edge sort (counting sort by dst) ----------------
__global__ __launch_bounds__(256) void k_hist(const int* __restrict__ ei, int* __restrict__ cnt) {
    int e = blockIdx.x * 256 + threadIdx.x;
    if (e < NE) atomicAdd(&cnt[ei[NE + e]], 1);
}

// two-level scan: block-local exclusive + block sums
__global__ __launch_bounds__(256) void k_scan1(const int* __restrict__ cnt,
                                               int* __restrict__ offs,
                                               int* __restrict__ bsum) {
    __shared__ int lds[256];
    int idx = blockIdx.x * 256 + threadIdx.x;
    int v = (idx < NN) ? cnt[idx] : 0;
    lds[threadIdx.x] = v;
    __syncthreads();
    #pragma unroll
    for (int off = 1; off < 256; off <<= 1) {
        int add = (threadIdx.x >= off) ? lds[threadIdx.x - off] : 0;
        __syncthreads();
        lds[threadIdx.x] += add;
        __syncthreads();
    }
    if (idx < NN) offs[idx] = lds[threadIdx.x] - v;
    if (threadIdx.x == 255) bsum[blockIdx.x] = lds[255];
}

__global__ __launch_bounds__(256) void k_scan2(const int* __restrict__ bsum,
                                               int* __restrict__ boff, int nblk) {
    __shared__ int lds[256];
    int v = (threadIdx.x < nblk) ? bsum[threadIdx.x] : 0;
    lds[threadIdx.x] = v;
    __syncthreads();
    #pragma unroll
    for (int off = 1; off < 256; off <<= 1) {
        int add = (threadIdx.x >= off) ? lds[threadIdx.x - off] : 0;
        __syncthreads();
        lds[threadIdx.x] += add;
        __syncthreads();
    }
    if (threadIdx.x < nblk) boff[threadIdx.x] = lds[threadIdx.x] - v;
}

__global__ __launch_bounds__(256) void k_scan3(int* __restrict__ offs,
                                               const int* __restrict__ boff,
                                               int* __restrict__ cursor) {
    int idx = blockIdx.x * 256 + threadIdx.x;
    if (idx < NN) {
        int o = offs[idx] + boff[blockIdx.x];
        offs[idx] = o;
        cursor[idx] = o;
    }
    if (idx == 0) offs[NN] = NE;
}

__global__ __launch_bounds__(256) void k_scatter(const int* __restrict__ ei,
                                                 const float* __restrict__ ea,
                                                 int* __restrict__ cursor,
                                                 int* __restrict__ ssrc,
                                                 float* __restrict__ sea) {
    int e = blockIdx.x * 256 + threadIdx.x;
    if (e < NE) {
        int d = ei[NE + e];
        int pos = atomicAdd(&cursor[d], 1);
        ssrc[pos] = ei[e];
        sea[pos] = ea[e];
    }
}

// ---------------- prep: fp32 -> bf16 cast (vectorized) ----------------
__global__ __launch_bounds__(256) void k_f2bf4(const float* __restrict__ in,
                                               ushort* __restrict__ out, int n4) {
    for (int i = blockIdx.x * 256 + threadIdx.x; i < n4; i += gridDim.x * 256) {
        float4 v = *reinterpret_cast<const float4*>(&in[(size_t)i * 4]);
        ushort4 o;
        o.x = f2bf(v.x); o.y = f2bf(v.y); o.z = f2bf(v.z); o.w = f2bf(v.w);
        *reinterpret_cast<ushort4*>(&out[(size_t)i * 4]) = o;
    }
}

// ---------------- prep: weight transpose + bf16 ([K][D] -> [D][K]) ----------------
struct WPrep {
    const float* src[8];
    ushort* dst[8];
    int K[8];
    int D[8];
};
__global__ __launch_bounds__(256) void k_wprep(WPrep p) {
    int m = blockIdx.y;
    int K = p.K[m], D = p.D[m];
    int n = K * D;
    for (int idx = blockIdx.x * 256 + threadIdx.x; idx < n; idx += gridDim.x * 256) {
        int c = idx / K, k = idx - c * K;
        p.dst[m][idx] = f2bf(p.src[m][(size_t)k * D + c]);
    }
}

// ---------------- fused 4-matrix MFMA GEMM ----------------
// C = Xb[M,K](bf16) @ Wt[4*DOUT,K](bf16, pre-transposed) + bias.
// Tile 128x64, 256 threads (4 waves in 2x2), 16x16x32 bf16 MFMA.
// Outputs: mat0 -> Oq (fp32), mat1 -> Ok (bf16), mat2 -> Ov (bf16), mat3 -> Oh (fp32).
template<int K, int DOUT>
__global__ __launch_bounds__(256) void k_gemm_mfma(
    const ushort* __restrict__ Xb, const ushort* __restrict__ Wt,
    const float* __restrict__ B0, const float* __restrict__ B1,
    const float* __restrict__ B2, const float* __restrict__ B3,
    float* __restrict__ Oq, ushort* __restrict__ Ok,
    ushort* __restrict__ Ov, float* __restrict__ Oh)
{
    constexpr int BM = 128, BN = 64, BK = 32;
    __shared__ ushort Xs[BM][BK + 8];    // row stride 80B: 16B-aligned, conflict-light
    __shared__ ushort Wss[BN][BK + 8];

    int row0 = blockIdx.x * BM;
    int col0 = blockIdx.y * BN;          // fused column (over 4*DOUT)
    int mat = col0 / DOUT;
    int mcol0 = col0 - mat * DOUT;
    const float* Bb = (mat == 0) ? B0 : (mat == 1) ? B1 : (mat == 2) ? B2 : B3;

    int t = threadIdx.x;
    int wid = t >> 6, lane = t & 63;
    int wr = wid >> 1, wc = wid & 1;     // wave covers rows wr*64..+64, cols wc*32..+32
    int lr = lane & 15, lk = lane >> 4;  // frag: A/B row|col = lr, k-group = lk

    f32x4 acc[4][2] = {};

    for (int k0 = 0; k0 < K; k0 += BK) {
        #pragma unroll
        for (int i = 0; i < 2; ++i) {    // X tile: 128x32 = 512 x (8 bf16 slots)
            int slot = t + i * 256;
            int r = slot >> 2, c8 = slot & 3;
            int gr = row0 + r;
            uint4 val = make_uint4(0, 0, 0, 0);
            if (gr < NN) val = *reinterpret_cast<const uint4*>(&Xb[(size_t)gr * K + k0 + c8 * 8]);
            *reinterpret_cast<uint4*>(&Xs[r][c8 * 8]) = val;
        }
        {                                 // W tile: 64x32 = 256 slots
            int r = t >> 2, c8 = t & 3;
            uint4 val = *reinterpret_cast<const uint4*>(&Wt[(size_t)(col0 + r) * K + k0 + c8 * 8]);
            *reinterpret_cast<uint4*>(&Wss[r][c8 * 8]) = val;
        }
        __syncthreads();
        bf16x8 a[4], b[2];
        #pragma unroll
        for (int m = 0; m < 4; ++m)
            a[m] = *reinterpret_cast<const bf16x8*>(&Xs[wr * 64 + m * 16 + lr][lk * 8]);
        #pragma unroll
        for (int n = 0; n < 2; ++n)
            b[n] = *reinterpret_cast<const bf16x8*>(&Wss[wc * 32 + n * 16 + lr][lk * 8]);
        #pragma unroll
        for (int m = 0; m < 4; ++m)
            #pragma unroll
            for (int n = 0; n < 2; ++n)
                acc[m][n] = __builtin_amdgcn_mfma_f32_16x16x32_bf16(a[m], b[n], acc[m][n], 0, 0, 0);
        __syncthreads();
    }

    // epilogue: C/D layout col=lane&15, row=(lane>>4)*4+reg  [verified mapping]
    #pragma unroll
    for (int m = 0; m < 4; ++m) {
        #pragma unroll
        for (int n = 0; n < 2; ++n) {
            int gcol = mcol0 + wc * 32 + n * 16 + lr;
            float bias = Bb[gcol];
            #pragma unroll
            for (int r = 0; r < 4; ++r) {
                int grow = row0 + wr * 64 + m * 16 + lk * 4 + r;
                if (grow >= NN) continue;
                float vv = acc[m][n][r] + bias;
                size_t oidx = (size_t)grow * DOUT + gcol;
                if (mat == 0) Oq[oidx] = vv;
                else if (mat == 1) Ok[oidx] = f2bf(vv);
                else if (mat == 2) Ov[oidx] = f2bf(vv);
                else Oh[oidx] = vv;
            }
        }
    }
}

// ---------------- per-node attention aggregate (1 wave / node, 2 passes, bf16 k/v) ----------------
template<int D>
__global__ __launch_bounds__(256) void k_attn(
    const float* __restrict__ q, const ushort* __restrict__ kb, const ushort* __restrict__ vb,
    const float* __restrict__ We,
    const int* __restrict__ ssrc, const float* __restrict__ sea,
    const int* __restrict__ offs,
    float* __restrict__ logits,
    float* __restrict__ hout)               // pre-loaded with skip; += attn out
{
    int wave = threadIdx.x >> 6;
    int lane = threadIdx.x & 63;
    int node = blockIdx.x * 4 + wave;
    if (node >= NN) return;
    int start = offs[node], stop = offs[node + 1];
    constexpr float inv_sqrt_d = (D == 256) ? 0.0625f : 0.125f;

    if constexpr (D == 256) {
        float4 qv = *reinterpret_cast<const float4*>(&q[(size_t)node * 256 + lane * 4]);
        float4 wel = *reinterpret_cast<const float4*>(&We[lane * 4]);
        float m = -1e30f;
        for (int i = start; i < stop; ++i) {
            int s = ssrc[i];
            float eav = sea[i];
            ushort4 ku = *reinterpret_cast<const ushort4*>(&kb[(size_t)s * 256 + lane * 4]);
            float dot = qv.x * (bf2f(ku.x) + eav * wel.x) + qv.y * (bf2f(ku.y) + eav * wel.y)
                      + qv.z * (bf2f(ku.z) + eav * wel.z) + qv.w * (bf2f(ku.w) + eav * wel.w);
            #pragma unroll
            for (int o = 32; o; o >>= 1) dot += __shfl_xor(dot, o);
            dot *= inv_sqrt_d;
            if (lane == 0) logits[i] = dot;
            m = fmaxf(m, dot);
        }
        float ssum = 0.f;
        float4 acc = make_float4(0.f, 0.f, 0.f, 0.f);
        for (int i = start; i < stop; ++i) {
            int s = ssrc[i];
            float eav = sea[i];
            float p = expf(logits[i] - m);
            ssum += p;
            ushort4 vu = *reinterpret_cast<const ushort4*>(&vb[(size_t)s * 256 + lane * 4]);
            acc.x += p * (bf2f(vu.x) + eav * wel.x);
            acc.y += p * (bf2f(vu.y) + eav * wel.y);
            acc.z += p * (bf2f(vu.z) + eav * wel.z);
            acc.w += p * (bf2f(vu.w) + eav * wel.w);
        }
        float inv = 1.0f / (ssum + 1e-16f);
        float* hp = &hout[(size_t)node * 256 + lane * 4];
        float4 cur = *reinterpret_cast<float4*>(hp);
        cur.x += acc.x * inv; cur.y += acc.y * inv;
        cur.z += acc.z * inv; cur.w += acc.w * inv;
        *reinterpret_cast<float4*>(hp) = cur;
    } else {
        float qv = q[(size_t)node * 64 + lane];
        float wel = We[lane];
        float m = -1e30f;
        for (int i = start; i < stop; ++i) {
            int s = ssrc[i];
            float eav = sea[i];
            float kv = bf2f(kb[(size_t)s * 64 + lane]);
            float dot = qv * (kv + eav * wel);
            #pragma unroll
            for (int o = 32; o; o >>= 1) dot += __shfl_xor(dot, o);
            dot *= inv_sqrt_d;
            if (lane == 0) logits[i] = dot;
            m = fmaxf(m, dot);
        }
        float ssum = 0.f, acc = 0.f;
        for (int i = start; i < stop; ++i) {
            int s = ssrc[i];
            float eav = sea[i];
            float p = expf(logits[i] - m);
            ssum += p;
            float vv = bf2f(vb[(size_t)s * 64 + lane]);
            acc += p * (vv + eav * wel);
        }
        float inv = 1.0f / (ssum + 1e-16f);
        hout[(size_t)node * 64 + lane] += acc * inv;
    }
}

// ---------------- BatchNorm ----------------
template<int D>
__global__ __launch_bounds__(256) void k_bnstats(const float* __restrict__ h,
                                                 float* __restrict__ sums,
                                                 int rows_per_block) {
    constexpr int NSUB = 256 / D;
    int col = threadIdx.x % D;
    int sub = threadIdx.x / D;
    int r0 = blockIdx.x * rows_per_block;
    int r1 = min(r0 + rows_per_block, NN);
    float s = 0.f, ss = 0.f;
    for (int r = r0 + sub; r < r1; r += NSUB) {
        float x = h[(size_t)r * D + col];
        s += x; ss += x * x;
    }
    atomicAdd(&sums[col], s);
    atomicAdd(&sums[D + col], ss);
}

template<int D>
__global__ void k_bnfin(const float* __restrict__ sums,
                        const float* __restrict__ gamma, const float* __restrict__ beta,
                        float* __restrict__ ab) {
    int c = threadIdx.x;
    if (c >= D) return;
    float mean = sums[c] / (float)NN;
    float var = sums[D + c] / (float)NN - mean * mean;
    float a = gamma[c] * rsqrtf(var + EPS_BN);
    ab[c] = a;
    ab[D + c] = beta[c] - mean * a;
}

// h0: normalize -> xs[:,0:256] (fp32) and h0b (bf16, layer-1 input)
__global__ __launch_bounds__(256) void k_bnapply0(float* __restrict__ h,
                                                  const float* __restrict__ ab,
                                                  float* __restrict__ xs,
                                                  ushort* __restrict__ h0b) {
    int idx = blockIdx.x * 256 + threadIdx.x;     // over NN*64 float4s
    int n = idx >> 6, c4 = idx & 63;
    float4 x4 = *reinterpret_cast<float4*>(&h[(size_t)idx * 4]);
    float4 a4 = *reinterpret_cast<const float4*>(&ab[c4 * 4]);
    float4 b4 = *reinterpret_cast<const float4*>(&ab[256 + c4 * 4]);
    float4 r;
    r.x = a4.x * x4.x + b4.x; r.y = a4.y * x4.y + b4.y;
    r.z = a4.z * x4.z + b4.z; r.w = a4.w * x4.w + b4.w;
    *reinterpret_cast<float4*>(&xs[(size_t)n * 320 + c4 * 4]) = r;
    ushort4 o;
    o.x = f2bf(r.x); o.y = f2bf(r.y); o.z = f2bf(r.z); o.w = f2bf(r.w);
    *reinterpret_cast<ushort4*>(&h0b[(size_t)idx * 4]) = o;
}

// h1: write only xs[:, 256:320]
__global__ __launch_bounds__(256) void k_bnapply1(const float* __restrict__ h,
                                                  const float* __restrict__ ab,
                                                  float* __restrict__ xs) {
    int idx = blockIdx.x * 256 + threadIdx.x;     // over NN*16 float4s
    int n = idx >> 4, c4 = idx & 15;
    float4 x4 = *reinterpret_cast<const float4*>(&h[(size_t)idx * 4]);
    float4 a4 = *reinterpret_cast<const float4*>(&ab[c4 * 4]);
    float4 b4 = *reinterpret_cast<const float4*>(&ab[64 + c4 * 4]);
    float4 r;
    r.x = a4.x * x4.x + b4.x; r.y = a4.y * x4.y + b4.y;
    r.z = a4.z * x4.z + b4.z; r.w = a4.w * x4.w + b4.w;
    *reinterpret_cast<float4*>(&xs[(size_t)n * 320 + 256 + c4 * 4]) = r;
}

// ---------------- global mean pool (1 block / graph, batch sorted) ----------------
__global__ __launch_bounds__(256) void k_pool(const float* __restrict__ xs,
                                              const int* __restrict__ batch,
                                              float* __restrict__ xpool) {
    int g = blockIdx.x;
    __shared__ int se[2];
    if (threadIdx.x < 2) {
        int target = g + threadIdx.x;
        int lo = 0, hi = NN;
        while (lo < hi) {
            int mid = (lo + hi) >> 1;
            if (batch[mid] < target) lo = mid + 1; else hi = mid;
        }
        se[threadIdx.x] = lo;
    }
    __syncthreads();
    int start = se[0], stop = se[1];
    float cnt = fmaxf((float)(stop - start), 1.0f);
    for (int c = threadIdx.x; c < 320; c += 256) {
        float s = 0.f;
        for (int r = start; r < stop; ++r) s += xs[(size_t)r * 320 + c];
        xpool[(size_t)g * 320 + c] = s / cnt;
    }
}

// ---------------- launch ----------------
extern "C" void kernel_launch(void* const* d_in, const int* in_sizes, int n_in,
                              void* d_out, int out_size, void* d_ws, size_t ws_size,
                              hipStream_t stream) {
    const float* x     = (const float*)d_in[0];
    const int*   ei    = (const int*)d_in[1];
    const float* ea    = (const float*)d_in[2];
    const int*   batch = (const int*)d_in[3];
    const float *Wq0 = (const float*)d_in[4],  *bq0 = (const float*)d_in[5];
    const float *Wk0 = (const float*)d_in[6],  *bk0 = (const float*)d_in[7];
    const float *Wv0 = (const float*)d_in[8],  *bv0 = (const float*)d_in[9];
    const float *We0 = (const float*)d_in[10];
    const float *Ws0 = (const float*)d_in[11], *bs0 = (const float*)d_in[12];
    const float *gamma0 = (const float*)d_in[13], *beta0 = (const float*)d_in[14];
    const float *Wq1 = (const float*)d_in[15], *bq1 = (const float*)d_in[16];
    const float *Wk1 = (const float*)d_in[17], *bk1 = (const float*)d_in[18];
    const float *Wv1 = (const float*)d_in[19], *bv1 = (const float*)d_in[20];
    const float *We1 = (const float*)d_in[21];
    const float *Ws1 = (const float*)d_in[22], *bs1 = (const float*)d_in[23];
    const float *gamma1 = (const float*)d_in[24], *beta1 = (const float*)d_in[25];

    char* ws = (char*)d_ws;
    size_t off = 0;
    auto alloc = [&](size_t bytes) -> char* {
        char* p = ws + off;
        off += (bytes + 255) & ~(size_t)255;
        return p;
    };
    float*  q0   = (float*)alloc((size_t)NN * D0 * 4);   // block reused for layer-1 buffers
    ushort* k0b  = (ushort*)alloc((size_t)NN * D0 * 2);
    ushort* v0b  = (ushort*)alloc((size_t)NN * D0 * 2);
    float*  h0   = (float*)alloc((size_t)NN * D0 * 4);
    ushort* xbuf = (ushort*)alloc((size_t)NN * D0 * 2);  // xb (layer0 in) then h0b (layer1 in)
    float* logits = (float*)alloc((size_t)NE * 4);
    float* sea    = (float*)alloc((size_t)NE * 4);
    int*   ssrc   = (int*)alloc((size_t)NE * 4);
    int*   cnt    = (int*)alloc((size_t)(NN + 1) * 4);
    int*   offs   = (int*)alloc((size_t)(NN + 1) * 4);
    int*   cursor = (int*)alloc((size_t)(NN + 1) * 4);
    int*   bsum   = (int*)alloc(256 * 4);
    int*   boff   = (int*)alloc(256 * 4);
    float* sums0  = (float*)alloc(2 * D0 * 4);
    float* ab0    = (float*)alloc(2 * D0 * 4);
    float* sums1  = (float*)alloc(2 * D1 * 4);
    float* ab1    = (float*)alloc(2 * D1 * 4);
    ushort* wt0   = (ushort*)alloc((size_t)4 * D0 * F_IN * 2);  // [1024][128]
    ushort* wt1   = (ushort*)alloc((size_t)4 * D1 * D0 * 2);    // [256][256]

    ushort* xb  = xbuf;                    // [NN][128] bf16
    ushort* h0b = xbuf;                    // [NN][256] bf16 (xb dead by then)

    // layer-1 buffers alias q0's block (q0 dead after attn0)
    float*  q1  = q0;
    ushort* k1b = (ushort*)(q0 + (size_t)NN * D1);
    ushort* v1b = k1b + (size_t)NN * D1;
    float*  h1  = (float*)(v1b + (size_t)NN * D1);

    float* xpool = (float*)d_out;
    float* xs = (float*)d_out + (size_t)NG * 320;

    const int NBLK = (NN + 255) / 256;   // 196

    // --- prep: edge sort + casts + weight transpose (independent of GEMM) ---
    hipMemsetAsync(cnt, 0, (NN + 1) * 4, stream);
    k_hist<<<(NE + 255) / 256, 256, 0, stream>>>(ei, cnt);
    k_scan1<<<NBLK, 256, 0, stream>>>(cnt, offs, bsum);
    k_scan2<<<1, 256, 0, stream>>>(bsum, boff, NBLK);
    k_scan3<<<NBLK, 256, 0, stream>>>(offs, boff, cursor);
    k_scatter<<<(NE + 255) / 256, 256, 0, stream>>>(ei, ea, cursor, ssrc, sea);

    k_f2bf4<<<2048, 256, 0, stream>>>(x, xb, NN * F_IN / 4);
    WPrep wp;
    wp.src[0] = Wq0; wp.src[1] = Wk0; wp.src[2] = Wv0; wp.src[3] = Ws0;
    wp.src[4] = Wq1; wp.src[5] = Wk1; wp.src[6] = Wv1; wp.src[7] = Ws1;
    for (int m = 0; m < 4; ++m) { wp.K[m] = F_IN; wp.D[m] = D0; wp.dst[m] = wt0 + (size_t)m * D0 * F_IN; }
    for (int m = 0; m < 4; ++m) { wp.K[4+m] = D0; wp.D[4+m] = D1; wp.dst[4+m] = wt1 + (size_t)m * D1 * D0; }
    k_wprep<<<dim3(64, 8), 256, 0, stream>>>(wp);

    // --- layer 0 ---
    k_gemm_mfma<F_IN, D0><<<dim3((NN + 127) / 128, 16), 256, 0, stream>>>(
        xb, wt0, bq0, bk0, bv0, bs0, q0, k0b, v0b, h0);
    k_attn<D0><<<(NN + 3) / 4, 256, 0, stream>>>(q0, k0b, v0b, We0, ssrc, sea, offs, logits, h0);
    hipMemsetAsync(sums0, 0, 2 * D0 * 4, stream);
    k_bnstats<D0><<<NBLK, 256, 0, stream>>>(h0, sums0, 256);
    k_bnfin<D0><<<1, D0, 0, stream>>>(sums0, gamma0, beta0, ab0);
    k_bnapply0<<<(NN * 64 + 255) / 256, 256, 0, stream>>>(h0, ab0, xs, h0b);

    // --- layer 1 ---
    k_gemm_mfma<D0, D1><<<dim3((NN + 127) / 128, 4), 256, 0, stream>>>(
        h0b, wt1, bq1, bk1, bv1, bs1, q1, k1b, v1b, h1);
    k_attn<D1><<<(NN + 3) / 4, 256, 0, stream>>>(q1, k1b, v1b, We1, ssrc, sea, offs, logits, h1);
    hipMemsetAsync(sums1, 0, 2 * D1 * 4, stream);
    k_bnstats<D1><<<NBLK, 256, 0, stream>>>(h1, sums1, 256);
    k_bnfin<D1><<<1, D1, 0, stream>>>(sums1, gamma1, beta1, ab1);
    k_bnapply1<<<(NN * 16 + 255) / 256, 256, 0, stream>>>(h1, ab1, xs);

    // --- pool ---
    k_pool<<<NG, 256, 0, stream>>>(xs, batch, xpool);
}

// Round 3
// 765.163 us; speedup vs baseline: 1.7114x; 1.2573x over previous
//
#include <hip/hip_runtime.h>

// Problem constants (match reference)
constexpr int NN = 50000;      // nodes
constexpr int NE = 800000;     // edges
constexpr int F_IN = 128;
constexpr int D0 = 256;
constexpr int D1 = 64;
constexpr int NG = 256;        // graphs
constexpr float EPS_BN = 1e-5f;

typedef __attribute__((ext_vector_type(8))) short bf16x8;
typedef __attribute__((ext_vector_type(4))) float f32x4;
typedef __attribute__((ext_vector_type(8))) ushort u16x8;
typedef __attribute__((ext_vector_type(4))) ushort u16x4;

__device__ inline ushort f2bf(float f) {
    uint32_t u = __float_as_uint(f);
    uint32_t r = u + 0x7fff + ((u >> 16) & 1);   // RNE
    return (ushort)(r >> 16);
}
__device__ inline float bf2f(ushort b) {
    return __uint_as_float((uint32_t)b << 16);
}

// ---------------- edge sort (counting sort by dst) ----------------
__global__ __launch_bounds__(256) void k_hist(const int* __restrict__ ei, int* __restrict__ cnt) {
    int e = blockIdx.x * 256 + threadIdx.x;
    if (e < NE) atomicAdd(&cnt[ei[NE + e]], 1);
}

__global__ __launch_bounds__(256) void k_scan1(const int* __restrict__ cnt,
                                               int* __restrict__ offs,
                                               int* __restrict__ bsum) {
    __shared__ int lds[256];
    int idx = blockIdx.x * 256 + threadIdx.x;
    int v = (idx < NN) ? cnt[idx] : 0;
    lds[threadIdx.x] = v;
    __syncthreads();
    #pragma unroll
    for (int off = 1; off < 256; off <<= 1) {
        int add = (threadIdx.x >= off) ? lds[threadIdx.x - off] : 0;
        __syncthreads();
        lds[threadIdx.x] += add;
        __syncthreads();
    }
    if (idx < NN) offs[idx] = lds[threadIdx.x] - v;
    if (threadIdx.x == 255) bsum[blockIdx.x] = lds[255];
}

__global__ __launch_bounds__(256) void k_scan2(const int* __restrict__ bsum,
                                               int* __restrict__ boff, int nblk) {
    __shared__ int lds[256];
    int v = (threadIdx.x < nblk) ? bsum[threadIdx.x] : 0;
    lds[threadIdx.x] = v;
    __syncthreads();
    #pragma unroll
    for (int off = 1; off < 256; off <<= 1) {
        int add = (threadIdx.x >= off) ? lds[threadIdx.x - off] : 0;
        __syncthreads();
        lds[threadIdx.x] += add;
        __syncthreads();
    }
    if (threadIdx.x < nblk) boff[threadIdx.x] = lds[threadIdx.x] - v;
}

__global__ __launch_bounds__(256) void k_scan3(int* __restrict__ offs,
                                               const int* __restrict__ boff,
                                               int* __restrict__ cursor) {
    int idx = blockIdx.x * 256 + threadIdx.x;
    if (idx < NN) {
        int o = offs[idx] + boff[blockIdx.x];
        offs[idx] = o;
        cursor[idx] = o;
    }
    if (idx == 0) offs[NN] = NE;
}

// pack (src, edge_attr bits) per sorted edge
__global__ __launch_bounds__(256) void k_scatter(const int* __restrict__ ei,
                                                 const float* __restrict__ ea,
                                                 int* __restrict__ cursor,
                                                 int2* __restrict__ sedge) {
    int e = blockIdx.x * 256 + threadIdx.x;
    if (e < NE) {
        int d = ei[NE + e];
        int pos = atomicAdd(&cursor[d], 1);
        sedge[pos] = make_int2(ei[e], __float_as_int(ea[e]));
    }
}

// ---------------- prep: fp32 -> bf16 cast (vectorized) ----------------
__global__ __launch_bounds__(256) void k_f2bf4(const float* __restrict__ in,
                                               ushort* __restrict__ out, int n4) {
    for (int i = blockIdx.x * 256 + threadIdx.x; i < n4; i += gridDim.x * 256) {
        float4 v = *reinterpret_cast<const float4*>(&in[(size_t)i * 4]);
        ushort4 o;
        o.x = f2bf(v.x); o.y = f2bf(v.y); o.z = f2bf(v.z); o.w = f2bf(v.w);
        *reinterpret_cast<ushort4*>(&out[(size_t)i * 4]) = o;
    }
}

// ---------------- prep: weight transpose + bf16 ([K][D] -> [D][K]) ----------------
struct WPrep {
    const float* src[8];
    ushort* dst[8];
    int K[8];
    int D[8];
};
__global__ __launch_bounds__(256) void k_wprep(WPrep p) {
    int m = blockIdx.y;
    int K = p.K[m], D = p.D[m];
    int n = K * D;
    for (int idx = blockIdx.x * 256 + threadIdx.x; idx < n; idx += gridDim.x * 256) {
        int c = idx / K, k = idx - c * K;
        p.dst[m][idx] = f2bf(p.src[m][(size_t)k * D + c]);
    }
}

// ---------------- fused 4-matrix MFMA GEMM ----------------
template<int K, int DOUT>
__global__ __launch_bounds__(256) void k_gemm_mfma(
    const ushort* __restrict__ Xb, const ushort* __restrict__ Wt,
    const float* __restrict__ B0, const float* __restrict__ B1,
    const float* __restrict__ B2, const float* __restrict__ B3,
    float* __restrict__ Oq, ushort* __restrict__ Ok,
    ushort* __restrict__ Ov, float* __restrict__ Oh)
{
    constexpr int BM = 128, BN = 64, BK = 32;
    __shared__ ushort Xs[BM][BK + 8];
    __shared__ ushort Wss[BN][BK + 8];

    int row0 = blockIdx.x * BM;
    int col0 = blockIdx.y * BN;
    int mat = col0 / DOUT;
    int mcol0 = col0 - mat * DOUT;
    const float* Bb = (mat == 0) ? B0 : (mat == 1) ? B1 : (mat == 2) ? B2 : B3;

    int t = threadIdx.x;
    int wid = t >> 6, lane = t & 63;
    int wr = wid >> 1, wc = wid & 1;
    int lr = lane & 15, lk = lane >> 4;

    f32x4 acc[4][2] = {};

    for (int k0 = 0; k0 < K; k0 += BK) {
        #pragma unroll
        for (int i = 0; i < 2; ++i) {
            int slot = t + i * 256;
            int r = slot >> 2, c8 = slot & 3;
            int gr = row0 + r;
            uint4 val = make_uint4(0, 0, 0, 0);
            if (gr < NN) val = *reinterpret_cast<const uint4*>(&Xb[(size_t)gr * K + k0 + c8 * 8]);
            *reinterpret_cast<uint4*>(&Xs[r][c8 * 8]) = val;
        }
        {
            int r = t >> 2, c8 = t & 3;
            uint4 val = *reinterpret_cast<const uint4*>(&Wt[(size_t)(col0 + r) * K + k0 + c8 * 8]);
            *reinterpret_cast<uint4*>(&Wss[r][c8 * 8]) = val;
        }
        __syncthreads();
        bf16x8 a[4], b[2];
        #pragma unroll
        for (int m = 0; m < 4; ++m)
            a[m] = *reinterpret_cast<const bf16x8*>(&Xs[wr * 64 + m * 16 + lr][lk * 8]);
        #pragma unroll
        for (int n = 0; n < 2; ++n)
            b[n] = *reinterpret_cast<const bf16x8*>(&Wss[wc * 32 + n * 16 + lr][lk * 8]);
        #pragma unroll
        for (int m = 0; m < 4; ++m)
            #pragma unroll
            for (int n = 0; n < 2; ++n)
                acc[m][n] = __builtin_amdgcn_mfma_f32_16x16x32_bf16(a[m], b[n], acc[m][n], 0, 0, 0);
        __syncthreads();
    }

    #pragma unroll
    for (int m = 0; m < 4; ++m) {
        #pragma unroll
        for (int n = 0; n < 2; ++n) {
            int gcol = mcol0 + wc * 32 + n * 16 + lr;
            float bias = Bb[gcol];
            #pragma unroll
            for (int r = 0; r < 4; ++r) {
                int grow = row0 + wr * 64 + m * 16 + lk * 4 + r;
                if (grow >= NN) continue;
                float vv = acc[m][n][r] + bias;
                size_t oidx = (size_t)grow * DOUT + gcol;
                if (mat == 0) Oq[oidx] = vv;
                else if (mat == 1) Ok[oidx] = f2bf(vv);
                else if (mat == 2) Ov[oidx] = f2bf(vv);
                else Oh[oidx] = vv;
            }
        }
    }
}

// ---------------- per-node attention: single pass, no-max softmax ----------------
// D=256: 2 lane-groups x 32 lanes (8 elems each); D=64: 4 groups x 16 lanes (4 elems).
// Software-pipelined gathers (prefetch next edge pair while computing current).
template<int D>
__global__ __launch_bounds__(256) void k_attn(
    const float* __restrict__ q, const ushort* __restrict__ kb, const ushort* __restrict__ vb,
    const float* __restrict__ We,
    const int2* __restrict__ sedge,
    const int* __restrict__ offs,
    float* __restrict__ hout)               // pre-loaded with skip; += attn out
{
    int wave = threadIdx.x >> 6;
    int lane = threadIdx.x & 63;
    int node = blockIdx.x * 4 + wave;
    if (node >= NN) return;
    int start = offs[node], stop = offs[node + 1];

    if constexpr (D == 256) {
        constexpr float scale = 0.0625f;
        int g = lane >> 5, sl = lane & 31;
        float q8[8], wel8[8];
        {
            float4 qa = *reinterpret_cast<const float4*>(&q[(size_t)node * 256 + sl * 8]);
            float4 qb = *reinterpret_cast<const float4*>(&q[(size_t)node * 256 + sl * 8 + 4]);
            q8[0] = qa.x; q8[1] = qa.y; q8[2] = qa.z; q8[3] = qa.w;
            q8[4] = qb.x; q8[5] = qb.y; q8[6] = qb.z; q8[7] = qb.w;
            float4 wa = *reinterpret_cast<const float4*>(&We[sl * 8]);
            float4 wb = *reinterpret_cast<const float4*>(&We[sl * 8 + 4]);
            wel8[0] = wa.x; wel8[1] = wa.y; wel8[2] = wa.z; wel8[3] = wa.w;
            wel8[4] = wb.x; wel8[5] = wb.y; wel8[6] = wb.z; wel8[7] = wb.w;
        }
        int deg = stop - start;
        int niter = (deg + 1) >> 1;
        float acc8[8] = {};
        float ssum = 0.f;

        int idx0 = start + g;
        bool val0 = idx0 < stop;
        int e0 = val0 ? idx0 : 0;
        int2 se0 = sedge[e0];
        u16x8 ku0 = *reinterpret_cast<const u16x8*>(&kb[(size_t)se0.x * 256 + sl * 8]);
        u16x8 vu0 = *reinterpret_cast<const u16x8*>(&vb[(size_t)se0.x * 256 + sl * 8]);

        for (int j = 0; j < niter; ++j) {
            // prefetch j+1
            int idx1 = start + 2 * (j + 1) + g;
            bool val1 = idx1 < stop;
            int e1 = val1 ? idx1 : 0;
            int2 se1 = sedge[e1];
            u16x8 ku1 = *reinterpret_cast<const u16x8*>(&kb[(size_t)se1.x * 256 + sl * 8]);
            u16x8 vu1 = *reinterpret_cast<const u16x8*>(&vb[(size_t)se1.x * 256 + sl * 8]);
            // compute on current
            float eav = __int_as_float(se0.y);
            float ew[8];
            float dot = 0.f;
            #pragma unroll
            for (int c = 0; c < 8; ++c) {
                ew[c] = eav * wel8[c];
                dot = fmaf(q8[c], bf2f((ushort)ku0[c]) + ew[c], dot);
            }
            #pragma unroll
            for (int o = 1; o <= 16; o <<= 1) dot += __shfl_xor(dot, o);
            float p = val0 ? __expf(dot * scale) : 0.f;
            ssum += p;
            #pragma unroll
            for (int c = 0; c < 8; ++c)
                acc8[c] = fmaf(p, bf2f((ushort)vu0[c]) + ew[c], acc8[c]);
            val0 = val1; se0 = se1; ku0 = ku1; vu0 = vu1;
        }
        // combine the two halves
        ssum += __shfl_xor(ssum, 32);
        #pragma unroll
        for (int c = 0; c < 8; ++c) acc8[c] += __shfl_xor(acc8[c], 32);
        float inv = 1.0f / (ssum + 1e-16f);
        float o4[4];
        #pragma unroll
        for (int c = 0; c < 4; ++c) o4[c] = g ? acc8[4 + c] : acc8[c];
        float* hp = &hout[(size_t)node * 256 + sl * 8 + g * 4];
        float4 cur = *reinterpret_cast<float4*>(hp);
        cur.x += o4[0] * inv; cur.y += o4[1] * inv;
        cur.z += o4[2] * inv; cur.w += o4[3] * inv;
        *reinterpret_cast<float4*>(hp) = cur;
    } else {
        constexpr float scale = 0.125f;
        int g = lane >> 4, sl = lane & 15;
        float q4[4], wel4[4];
        {
            float4 qa = *reinterpret_cast<const float4*>(&q[(size_t)node * 64 + sl * 4]);
            q4[0] = qa.x; q4[1] = qa.y; q4[2] = qa.z; q4[3] = qa.w;
            float4 wa = *reinterpret_cast<const float4*>(&We[sl * 4]);
            wel4[0] = wa.x; wel4[1] = wa.y; wel4[2] = wa.z; wel4[3] = wa.w;
        }
        int deg = stop - start;
        int niter = (deg + 3) >> 2;
        float acc4[4] = {};
        float ssum = 0.f;

        int idx0 = start + g;
        bool val0 = idx0 < stop;
        int e0 = val0 ? idx0 : 0;
        int2 se0 = sedge[e0];
        u16x4 ku0 = *reinterpret_cast<const u16x4*>(&kb[(size_t)se0.x * 64 + sl * 4]);
        u16x4 vu0 = *reinterpret_cast<const u16x4*>(&vb[(size_t)se0.x * 64 + sl * 4]);

        for (int j = 0; j < niter; ++j) {
            int idx1 = start + 4 * (j + 1) + g;
            bool val1 = idx1 < stop;
            int e1 = val1 ? idx1 : 0;
            int2 se1 = sedge[e1];
            u16x4 ku1 = *reinterpret_cast<const u16x4*>(&kb[(size_t)se1.x * 64 + sl * 4]);
            u16x4 vu1 = *reinterpret_cast<const u16x4*>(&vb[(size_t)se1.x * 64 + sl * 4]);
            float eav = __int_as_float(se0.y);
            float ew[4];
            float dot = 0.f;
            #pragma unroll
            for (int c = 0; c < 4; ++c) {
                ew[c] = eav * wel4[c];
                dot = fmaf(q4[c], bf2f((ushort)ku0[c]) + ew[c], dot);
            }
            #pragma unroll
            for (int o = 1; o <= 8; o <<= 1) dot += __shfl_xor(dot, o);
            float p = val0 ? __expf(dot * scale) : 0.f;
            ssum += p;
            #pragma unroll
            for (int c = 0; c < 4; ++c)
                acc4[c] = fmaf(p, bf2f((ushort)vu0[c]) + ew[c], acc4[c]);
            val0 = val1; se0 = se1; ku0 = ku1; vu0 = vu1;
        }
        // combine 4 groups (xor16 then xor32)
        ssum += __shfl_xor(ssum, 16);
        ssum += __shfl_xor(ssum, 32);
        #pragma unroll
        for (int c = 0; c < 4; ++c) {
            acc4[c] += __shfl_xor(acc4[c], 16);
            acc4[c] += __shfl_xor(acc4[c], 32);
        }
        float inv = 1.0f / (ssum + 1e-16f);
        float av = acc4[0];
        av = (g == 1) ? acc4[1] : av;
        av = (g == 2) ? acc4[2] : av;
        av = (g == 3) ? acc4[3] : av;
        hout[(size_t)node * 64 + sl * 4 + g] += av * inv;
    }
}

// ---------------- BatchNorm ----------------
template<int D>
__global__ __launch_bounds__(256) void k_bnstats(const float* __restrict__ h,
                                                 float* __restrict__ sums,
                                                 int rows_per_block) {
    constexpr int NSUB = 256 / D;
    int col = threadIdx.x % D;
    int sub = threadIdx.x / D;
    int r0 = blockIdx.x * rows_per_block;
    int r1 = min(r0 + rows_per_block, NN);
    float s = 0.f, ss = 0.f;
    for (int r = r0 + sub; r < r1; r += NSUB) {
        float x = h[(size_t)r * D + col];
        s += x; ss += x * x;
    }
    atomicAdd(&sums[col], s);
    atomicAdd(&sums[D + col], ss);
}

template<int D>
__global__ void k_bnfin(const float* __restrict__ sums,
                        const float* __restrict__ gamma, const float* __restrict__ beta,
                        float* __restrict__ ab) {
    int c = threadIdx.x;
    if (c >= D) return;
    float mean = sums[c] / (float)NN;
    float var = sums[D + c] / (float)NN - mean * mean;
    float a = gamma[c] * rsqrtf(var + EPS_BN);
    ab[c] = a;
    ab[D + c] = beta[c] - mean * a;
}

__global__ __launch_bounds__(256) void k_bnapply0(float* __restrict__ h,
                                                  const float* __restrict__ ab,
                                                  float* __restrict__ xs,
                                                  ushort* __restrict__ h0b) {
    int idx = blockIdx.x * 256 + threadIdx.x;     // over NN*64 float4s
    int n = idx >> 6, c4 = idx & 63;
    float4 x4 = *reinterpret_cast<float4*>(&h[(size_t)idx * 4]);
    float4 a4 = *reinterpret_cast<const float4*>(&ab[c4 * 4]);
    float4 b4 = *reinterpret_cast<const float4*>(&ab[256 + c4 * 4]);
    float4 r;
    r.x = a4.x * x4.x + b4.x; r.y = a4.y * x4.y + b4.y;
    r.z = a4.z * x4.z + b4.z; r.w = a4.w * x4.w + b4.w;
    *reinterpret_cast<float4*>(&xs[(size_t)n * 320 + c4 * 4]) = r;
    ushort4 o;
    o.x = f2bf(r.x); o.y = f2bf(r.y); o.z = f2bf(r.z); o.w = f2bf(r.w);
    *reinterpret_cast<ushort4*>(&h0b[(size_t)idx * 4]) = o;
}

__global__ __launch_bounds__(256) void k_bnapply1(const float* __restrict__ h,
                                                  const float* __restrict__ ab,
                                                  float* __restrict__ xs) {
    int idx = blockIdx.x * 256 + threadIdx.x;     // over NN*16 float4s
    int n = idx >> 4, c4 = idx & 15;
    float4 x4 = *reinterpret_cast<const float4*>(&h[(size_t)idx * 4]);
    float4 a4 = *reinterpret_cast<const float4*>(&ab[c4 * 4]);
    float4 b4 = *reinterpret_cast<const float4*>(&ab[64 + c4 * 4]);
    float4 r;
    r.x = a4.x * x4.x + b4.x; r.y = a4.y * x4.y + b4.y;
    r.z = a4.z * x4.z + b4.z; r.w = a4.w * x4.w + b4.w;
    *reinterpret_cast<float4*>(&xs[(size_t)n * 320 + 256 + c4 * 4]) = r;
}

// ---------------- global mean pool ----------------
__global__ __launch_bounds__(256) void k_pool(const float* __restrict__ xs,
                                              const int* __restrict__ batch,
                                              float* __restrict__ xpool) {
    int g = blockIdx.x;
    __shared__ int se[2];
    if (threadIdx.x < 2) {
        int target = g + threadIdx.x;
        int lo = 0, hi = NN;
        while (lo < hi) {
            int mid = (lo + hi) >> 1;
            if (batch[mid] < target) lo = mid + 1; else hi = mid;
        }
        se[threadIdx.x] = lo;
    }
    __syncthreads();
    int start = se[0], stop = se[1];
    float cnt = fmaxf((float)(stop - start), 1.0f);
    for (int c = threadIdx.x; c < 320; c += 256) {
        float s = 0.f;
        for (int r = start; r < stop; ++r) s += xs[(size_t)r * 320 + c];
        xpool[(size_t)g * 320 + c] = s / cnt;
    }
}

// ---------------- launch ----------------
extern "C" void kernel_launch(void* const* d_in, const int* in_sizes, int n_in,
                              void* d_out, int out_size, void* d_ws, size_t ws_size,
                              hipStream_t stream) {
    const float* x     = (const float*)d_in[0];
    const int*   ei    = (const int*)d_in[1];
    const float* ea    = (const float*)d_in[2];
    const int*   batch = (const int*)d_in[3];
    const float *Wq0 = (const float*)d_in[4],  *bq0 = (const float*)d_in[5];
    const float *Wk0 = (const float*)d_in[6],  *bk0 = (const float*)d_in[7];
    const float *Wv0 = (const float*)d_in[8],  *bv0 = (const float*)d_in[9];
    const float *We0 = (const float*)d_in[10];
    const float *Ws0 = (const float*)d_in[11], *bs0 = (const float*)d_in[12];
    const float *gamma0 = (const float*)d_in[13], *beta0 = (const float*)d_in[14];
    const float *Wq1 = (const float*)d_in[15], *bq1 = (const float*)d_in[16];
    const float *Wk1 = (const float*)d_in[17], *bk1 = (const float*)d_in[18];
    const float *Wv1 = (const float*)d_in[19], *bv1 = (const float*)d_in[20];
    const float *We1 = (const float*)d_in[21];
    const float *Ws1 = (const float*)d_in[22], *bs1 = (const float*)d_in[23];
    const float *gamma1 = (const float*)d_in[24], *beta1 = (const float*)d_in[25];

    char* ws = (char*)d_ws;
    size_t off = 0;
    auto alloc = [&](size_t bytes) -> char* {
        char* p = ws + off;
        off += (bytes + 255) & ~(size_t)255;
        return p;
    };
    float*  q0   = (float*)alloc((size_t)NN * D0 * 4);   // block reused for layer-1 buffers
    ushort* k0b  = (ushort*)alloc((size_t)NN * D0 * 2);
    ushort* v0b  = (ushort*)alloc((size_t)NN * D0 * 2);
    float*  h0   = (float*)alloc((size_t)NN * D0 * 4);
    ushort* xbuf = (ushort*)alloc((size_t)NN * D0 * 2);  // xb (layer0 in) then h0b (layer1 in)
    int2*  sedge = (int2*)alloc((size_t)NE * 8);
    int*   cnt    = (int*)alloc((size_t)(NN + 1) * 4);
    int*   offs   = (int*)alloc((size_t)(NN + 1) * 4);
    int*   cursor = (int*)alloc((size_t)(NN + 1) * 4);
    int*   bsum   = (int*)alloc(256 * 4);
    int*   boff   = (int*)alloc(256 * 4);
    float* sums0  = (float*)alloc(2 * D0 * 4);
    float* ab0    = (float*)alloc(2 * D0 * 4);
    float* sums1  = (float*)alloc(2 * D1 * 4);
    float* ab1    = (float*)alloc(2 * D1 * 4);
    ushort* wt0   = (ushort*)alloc((size_t)4 * D0 * F_IN * 2);  // [1024][128]
    ushort* wt1   = (ushort*)alloc((size_t)4 * D1 * D0 * 2);    // [256][256]

    ushort* xb  = xbuf;                    // [NN][128] bf16
    ushort* h0b = xbuf;                    // [NN][256] bf16 (xb dead by then)

    float*  q1  = q0;
    ushort* k1b = (ushort*)(q0 + (size_t)NN * D1);
    ushort* v1b = k1b + (size_t)NN * D1;
    float*  h1  = (float*)(v1b + (size_t)NN * D1);

    float* xpool = (float*)d_out;
    float* xs = (float*)d_out + (size_t)NG * 320;

    const int NBLK = (NN + 255) / 256;   // 196
    const int BN_BLK = (NN + 63) / 64;   // 782

    // --- prep ---
    hipMemsetAsync(cnt, 0, (NN + 1) * 4, stream);
    k_hist<<<(NE + 255) / 256, 256, 0, stream>>>(ei, cnt);
    k_scan1<<<NBLK, 256, 0, stream>>>(cnt, offs, bsum);
    k_scan2<<<1, 256, 0, stream>>>(bsum, boff, NBLK);
    k_scan3<<<NBLK, 256, 0, stream>>>(offs, boff, cursor);
    k_scatter<<<(NE + 255) / 256, 256, 0, stream>>>(ei, ea, cursor, sedge);

    k_f2bf4<<<2048, 256, 0, stream>>>(x, xb, NN * F_IN / 4);
    WPrep wp;
    wp.src[0] = Wq0; wp.src[1] = Wk0; wp.src[2] = Wv0; wp.src[3] = Ws0;
    wp.src[4] = Wq1; wp.src[5] = Wk1; wp.src[6] = Wv1; wp.src[7] = Ws1;
    for (int m = 0; m < 4; ++m) { wp.K[m] = F_IN; wp.D[m] = D0; wp.dst[m] = wt0 + (size_t)m * D0 * F_IN; }
    for (int m = 0; m < 4; ++m) { wp.K[4+m] = D0; wp.D[4+m] = D1; wp.dst[4+m] = wt1 + (size_t)m * D1 * D0; }
    k_wprep<<<dim3(64, 8), 256, 0, stream>>>(wp);

    // --- layer 0 ---
    k_gemm_mfma<F_IN, D0><<<dim3((NN + 127) / 128, 16), 256, 0, stream>>>(
        xb, wt0, bq0, bk0, bv0, bs0, q0, k0b, v0b, h0);
    k_attn<D0><<<(NN + 3) / 4, 256, 0, stream>>>(q0, k0b, v0b, We0, sedge, offs, h0);
    hipMemsetAsync(sums0, 0, 2 * D0 * 4, stream);
    k_bnstats<D0><<<BN_BLK, 256, 0, stream>>>(h0, sums0, 64);
    k_bnfin<D0><<<1, D0, 0, stream>>>(sums0, gamma0, beta0, ab0);
    k_bnapply0<<<(NN * 64 + 255) / 256, 256, 0, stream>>>(h0, ab0, xs, h0b);

    // --- layer 1 ---
    k_gemm_mfma<D0, D1><<<dim3((NN + 127) / 128, 4), 256, 0, stream>>>(
        h0b, wt1, bq1, bk1, bv1, bs1, q1, k1b, v1b, h1);
    k_attn<D1><<<(NN + 3) / 4, 256, 0, stream>>>(q1, k1b, v1b, We1, sedge, offs, h1);
    hipMemsetAsync(sums1, 0, 2 * D1 * 4, stream);
    k_bnstats<D1><<<BN_BLK, 256, 0, stream>>>(h1, sums1, 64);
    k_bnfin<D1><<<1, D1, 0, stream>>>(sums1, gamma1, beta1, ab1);
    k_bnapply1<<<(NN * 16 + 255) / 256, 256, 0, stream>>>(h1, ab1, xs);

    // --- pool ---
    k_pool<<<NG, 256, 0, stream>>>(xs, batch, xpool);
}